// Round 4
// baseline (100.943 us; speedup 1.0000x reference)
//
#include <hip/hip_runtime.h>

typedef _Float16 half4_t __attribute__((ext_vector_type(4)));
typedef _Float16 half8_t __attribute__((ext_vector_type(8)));
typedef float    f32x4  __attribute__((ext_vector_type(4)));

#define FS 136           // f16 row stride: 136 halfs = 272 B
#define EPS_V 1e-8f

__device__ __forceinline__ half8_t cvt8(float4 a, float4 b) {
    half8_t h;
    h[0] = (_Float16)a.x; h[1] = (_Float16)a.y; h[2] = (_Float16)a.z; h[3] = (_Float16)a.w;
    h[4] = (_Float16)b.x; h[5] = (_Float16)b.y; h[6] = (_Float16)b.z; h[7] = (_Float16)b.w;
    return h;
}

// out[b,c,m,n] = gamma * sum_h Fy[m,h] * sum_w img[h,w] * Fx[n,w]
__global__ __launch_bounds__(256) void glimpse_kernel(
    const float* __restrict__ vec,   // (4096, 3)
    const float* __restrict__ img,   // (4096, 2, 128, 128)
    float* __restrict__ out)         // (4096, 2, 12, 12)
{
    const int bc   = blockIdx.x;
    const int b    = bc >> 1;
    const int t    = threadIdx.x;
    const int lane = t & 63;
    const int wv   = t >> 6;
    const int fr   = lane & 15;      // fragment row/col
    const int fq   = lane >> 4;      // fragment k-quad (0..3)

    __shared__ __align__(16) _Float16 sFx[16 * FS];    // Fx rows 0..11, 12..15 zero
    __shared__ __align__(16) _Float16 sFy[16 * FS];    // Fy*gamma rows 0..11, 12..15 zero
    __shared__ __align__(16) _Float16 sTmp[16 * FS];   // sTmp[n][h]
    __shared__ __align__(16) float    sOut[144];

    // ---------- issue fragment loads straight from global (32 B/lane each) ----------
    const int m0 = wv * 32;
    const float* gbase  = img + (size_t)bc * 16384;
    const float* rbase0 = gbase + (m0 + fr) * 128      + fq * 8;
    const float* rbase1 = gbase + (m0 + 16 + fr) * 128 + fq * 8;
    float4 lo0[4], hi0[4], lo1[4], hi1[4];
    #pragma unroll
    for (int kt = 0; kt < 4; ++kt) {
        lo0[kt] = *reinterpret_cast<const float4*>(rbase0 + kt * 32);
        hi0[kt] = *reinterpret_cast<const float4*>(rbase0 + kt * 32 + 4);
        lo1[kt] = *reinterpret_cast<const float4*>(rbase1 + kt * 32);
        hi1[kt] = *reinterpret_cast<const float4*>(rbase1 + kt * 32 + 4);
    }

    // ---------- filters (hide under load latency) ----------
    const float gx_ = vec[b * 3 + 0];
    const float gy_ = vec[b * 3 + 1];
    const float ld  = vec[b * 3 + 2];
    const float delta = 4.0f * (ld + 1.0f);
    const float gx = 64.0f * (gx_ + 1.0f);
    const float gy = 64.0f * (gy_ + 1.0f);

    if (t < 192) {
        const int row24 = t >> 3;            // 0..23
        const int q     = t & 7;             // 16-w segment
        const bool isFy = row24 >= 12;
        const int  nm   = isFy ? row24 - 12 : row24;
        const float mu  = (isFy ? gy : gx) + ((float)nm - 6.5f) * delta;
        const float a0f = (float)(16 * q);

        float s = 0.f;
        #pragma unroll
        for (int j = 0; j < 16; ++j) {
            float d = (a0f + (float)j) - mu;
            s += __expf(-d * d * 0.25f);
        }
        s += __shfl_xor(s, 1);
        s += __shfl_xor(s, 2);
        s += __shfl_xor(s, 4);
        float inv = 1.0f / fmaxf(s, EPS_V);
        if (isFy) inv *= 4.0f;               // fold gamma into Fy

        _Float16* dst = (isFy ? sFy : sFx) + nm * FS + 16 * q;
        half8_t h0, h1;
        #pragma unroll
        for (int j = 0; j < 8; ++j) {
            float d = (a0f + (float)j) - mu;
            h0[j] = (_Float16)(__expf(-d * d * 0.25f) * inv);
        }
        #pragma unroll
        for (int j = 0; j < 8; ++j) {
            float d = (a0f + (float)(8 + j)) - mu;
            h1[j] = (_Float16)(__expf(-d * d * 0.25f) * inv);
        }
        *reinterpret_cast<half8_t*>(dst)     = h0;
        *reinterpret_cast<half8_t*>(dst + 8) = h1;
    } else {
        // zero rows 12..15 of sFx and sFy (68 half8-slots each)
        int u = t - 192;                     // 0..63
        half8_t z = {};
        for (int k = u; k < 136; k += 64) {
            _Float16* base = (k < 68 ? sFx : sFy) + 12 * FS;
            int s = (k < 68) ? k : k - 68;
            *reinterpret_cast<half8_t*>(base + s * 8) = z;
        }
    }
    __syncthreads();

    // ---------- phase 1: tmp = img(128x128) * Fx^T via MFMA, frags from registers ----------
    half8_t bfrag[4];
    #pragma unroll
    for (int kt = 0; kt < 4; ++kt)
        bfrag[kt] = *reinterpret_cast<const half8_t*>(&sFx[fr * FS + kt * 32 + 8 * fq]);

    f32x4 acc0 = {0.f, 0.f, 0.f, 0.f};
    f32x4 acc1 = {0.f, 0.f, 0.f, 0.f};
    #pragma unroll
    for (int kt = 0; kt < 4; ++kt) {
        half8_t a0 = cvt8(lo0[kt], hi0[kt]);
        half8_t a1 = cvt8(lo1[kt], hi1[kt]);
        acc0 = __builtin_amdgcn_mfma_f32_16x16x32_f16(a0, bfrag[kt], acc0, 0, 0, 0);
        acc1 = __builtin_amdgcn_mfma_f32_16x16x32_f16(a1, bfrag[kt], acc1, 0, 0, 0);
    }

    // D layout: lane holds tmp[h = m0 + mt*16 + fq*4 + r][n = fr]; store n-major
    {
        half4_t d0, d1;
        #pragma unroll
        for (int r = 0; r < 4; ++r) { d0[r] = (_Float16)acc0[r]; d1[r] = (_Float16)acc1[r]; }
        *reinterpret_cast<half4_t*>(&sTmp[fr * FS + m0 + fq * 4])      = d0;
        *reinterpret_cast<half4_t*>(&sTmp[fr * FS + m0 + 16 + fq * 4]) = d1;
    }
    __syncthreads();

    // ---------- phase 2: out = Fy'(16x128) * tmp(128x16), wave 0 only ----------
    if (wv == 0) {
        f32x4 acc = {0.f, 0.f, 0.f, 0.f};
        #pragma unroll
        for (int kt = 0; kt < 4; ++kt) {
            half8_t a  = *reinterpret_cast<const half8_t*>(&sFy[fr * FS + kt * 32 + 8 * fq]);
            half8_t bb = *reinterpret_cast<const half8_t*>(&sTmp[fr * FS + kt * 32 + 8 * fq]);
            acc = __builtin_amdgcn_mfma_f32_16x16x32_f16(a, bb, acc, 0, 0, 0);
        }
        // C[m = fq*4 + r][n = fr]; stage to LDS, then coalesced float4 store
        if (fr < 12 && fq < 3) {
            #pragma unroll
            for (int r = 0; r < 4; ++r)
                sOut[(fq * 4 + r) * 12 + fr] = acc[r];
        }
        // same-wave LDS write->read: lgkmcnt ordering suffices, no barrier
        if (lane < 36) {
            float4 v = *reinterpret_cast<const float4*>(&sOut[lane * 4]);
            *reinterpret_cast<float4*>(out + (size_t)bc * 144 + lane * 4) = v;
        }
    }
}

extern "C" void kernel_launch(void* const* d_in, const int* in_sizes, int n_in,
                              void* d_out, int out_size, void* d_ws, size_t ws_size,
                              hipStream_t stream) {
    const float* vec = (const float*)d_in[0];  // (4096,3) f32
    const float* img = (const float*)d_in[1];  // (4096,2,128,128) f32
    float* out = (float*)d_out;                // (4096,2,12,12) f32
    (void)in_sizes; (void)n_in; (void)out_size; (void)d_ws; (void)ws_size;

    glimpse_kernel<<<8192, 256, 0, stream>>>(vec, img, out);
}

// Round 5
// 99.952 us; speedup vs baseline: 1.0099x; 1.0099x over previous
//
#include <hip/hip_runtime.h>

typedef _Float16 half4_t __attribute__((ext_vector_type(4)));
typedef _Float16 half8_t __attribute__((ext_vector_type(8)));
typedef float    f32x4  __attribute__((ext_vector_type(4)));

#define FS 136           // f16 row stride: 136 halfs = 272 B (17 x 16B -> bank rotation)
#define EPS_V 1e-8f

// out[b,c,m,n] = gamma * sum_h Fy[m,h] * sum_w img[h,w] * Fx[n,w]
__global__ __launch_bounds__(256, 4) void glimpse_kernel(
    const float* __restrict__ vec,   // (4096, 3)
    const float* __restrict__ img,   // (4096, 2, 128, 128)
    float* __restrict__ out)         // (4096, 2, 12, 12)
{
    const int bc   = blockIdx.x;
    const int b    = bc >> 1;
    const int t    = threadIdx.x;
    const int lane = t & 63;
    const int wv   = t >> 6;
    const int fr   = lane & 15;      // fragment row/col index
    const int fq   = lane >> 4;      // fragment k-quad (0..3)

    __shared__ __align__(16) _Float16 sImg[128 * FS];  // 34.8 KB
    __shared__ __align__(16) _Float16 sTmp[16 * FS];   // 4.4 KB, sTmp[n][h]
    __shared__ __align__(16) float    sOut[144];

    // ---------- 1. issue wave-coalesced loads: wave wv owns rows [32wv, 32wv+32) ----------
    const int m0 = wv * 32;
    const float4* gw = reinterpret_cast<const float4*>(img + (size_t)bc * 16384 + (size_t)m0 * 128);
    float4 v[16];
    #pragma unroll
    for (int i = 0; i < 16; ++i) v[i] = gw[i * 64 + lane];   // 1 KB contiguous per instr

    // ---------- 2. filter scalars ----------
    const float gx_ = vec[b * 3 + 0];
    const float gy_ = vec[b * 3 + 1];
    const float ld  = vec[b * 3 + 2];
    const float delta = 4.0f * (ld + 1.0f);
    const float gx = 64.0f * (gx_ + 1.0f);
    const float gy = 64.0f * (gy_ + 1.0f);

    // ---------- 3. Fx B-fragments fully in registers (hides under load latency) ----------
    // lane (fr,fq) holds Fx[n=fr][w = kt*32 + 8*fq + j]; row-sum reduced over the
    // 4 lanes sharing fr (xor 16, 32). Two-pass exp keeps VGPR < 128.
    half8_t bfrag[4];
    {
        const float mux = gx + ((float)fr - 6.5f) * delta;
        float s = 0.f;
        #pragma unroll
        for (int kt = 0; kt < 4; ++kt) {
            #pragma unroll
            for (int j = 0; j < 8; ++j) {
                float d = (float)(kt * 32 + 8 * fq + j) - mux;
                s += __expf(-d * d * 0.25f);
            }
        }
        s += __shfl_xor(s, 16);
        s += __shfl_xor(s, 32);
        const float inv = 1.0f / fmaxf(s, EPS_V);
        #pragma unroll
        for (int kt = 0; kt < 4; ++kt) {
            #pragma unroll
            for (int j = 0; j < 8; ++j) {
                float d = (float)(kt * 32 + 8 * fq + j) - mux;
                bfrag[kt][j] = (_Float16)(__expf(-d * d * 0.25f) * inv);
            }
            if (fr >= 12) bfrag[kt] = half8_t{};   // pad cols 12..15 exact-zero
        }
    }

    // ---------- 4. cvt f32->f16, stage into wave-private LDS region ----------
    #pragma unroll
    for (int i = 0; i < 16; ++i) {
        int idx = i * 64 + lane;         // float4 index in wave region
        int rr  = idx >> 5;              // row 0..31
        int cc  = idx & 31;              // float4 col
        half4_t h;
        h[0] = (_Float16)v[i].x; h[1] = (_Float16)v[i].y;
        h[2] = (_Float16)v[i].z; h[3] = (_Float16)v[i].w;
        *reinterpret_cast<half4_t*>(&sImg[(m0 + rr) * FS + cc * 4]) = h;
    }
    // wave-private write->read: in-wave DS ordering via explicit lgkmcnt drain, no barrier
    asm volatile("s_waitcnt lgkmcnt(0)" ::: "memory");
    __builtin_amdgcn_sched_barrier(0);

    // ---------- 5. phase 1: tmp = img(32x128) * Fx^T via MFMA ----------
    f32x4 acc0 = {0.f, 0.f, 0.f, 0.f};
    f32x4 acc1 = {0.f, 0.f, 0.f, 0.f};
    #pragma unroll
    for (int kt = 0; kt < 4; ++kt) {
        half8_t a0 = *reinterpret_cast<const half8_t*>(&sImg[(m0 + fr) * FS      + kt * 32 + 8 * fq]);
        half8_t a1 = *reinterpret_cast<const half8_t*>(&sImg[(m0 + 16 + fr) * FS + kt * 32 + 8 * fq]);
        acc0 = __builtin_amdgcn_mfma_f32_16x16x32_f16(a0, bfrag[kt], acc0, 0, 0, 0);
        acc1 = __builtin_amdgcn_mfma_f32_16x16x32_f16(a1, bfrag[kt], acc1, 0, 0, 0);
    }
    // D: lane holds tmp[h = m0 + mt*16 + fq*4 + r][n = fr]; store n-major
    {
        half4_t d0, d1;
        #pragma unroll
        for (int r = 0; r < 4; ++r) { d0[r] = (_Float16)acc0[r]; d1[r] = (_Float16)acc1[r]; }
        *reinterpret_cast<half4_t*>(&sTmp[fr * FS + m0 + fq * 4])      = d0;
        *reinterpret_cast<half4_t*>(&sTmp[fr * FS + m0 + 16 + fq * 4]) = d1;
    }
    __syncthreads();   // only block-wide barrier; vmcnt already 0 here

    // ---------- 6. phase 2: out = Fy'(16x128) * tmp(128x16), wave 0 only ----------
    if (wv == 0) {
        // Fy A-fragments in registers (gamma=4 folded)
        half8_t afy[4];
        {
            const float muy = gy + ((float)fr - 6.5f) * delta;
            float s = 0.f;
            #pragma unroll
            for (int kt = 0; kt < 4; ++kt) {
                #pragma unroll
                for (int j = 0; j < 8; ++j) {
                    float d = (float)(kt * 32 + 8 * fq + j) - muy;
                    s += __expf(-d * d * 0.25f);
                }
            }
            s += __shfl_xor(s, 16);
            s += __shfl_xor(s, 32);
            const float inv = 4.0f / fmaxf(s, EPS_V);
            #pragma unroll
            for (int kt = 0; kt < 4; ++kt) {
                #pragma unroll
                for (int j = 0; j < 8; ++j) {
                    float d = (float)(kt * 32 + 8 * fq + j) - muy;
                    afy[kt][j] = (_Float16)(__expf(-d * d * 0.25f) * inv);
                }
                if (fr >= 12) afy[kt] = half8_t{};
            }
        }
        f32x4 acc = {0.f, 0.f, 0.f, 0.f};
        #pragma unroll
        for (int kt = 0; kt < 4; ++kt) {
            half8_t bb = *reinterpret_cast<const half8_t*>(&sTmp[fr * FS + kt * 32 + 8 * fq]);
            acc = __builtin_amdgcn_mfma_f32_16x16x32_f16(afy[kt], bb, acc, 0, 0, 0);
        }
        // C[m = fq*4 + r][n = fr] -> LDS bounce -> coalesced float4 store
        if (fr < 12 && fq < 3) {
            #pragma unroll
            for (int r = 0; r < 4; ++r)
                sOut[(fq * 4 + r) * 12 + fr] = acc[r];
        }
        asm volatile("s_waitcnt lgkmcnt(0)" ::: "memory");
        __builtin_amdgcn_sched_barrier(0);
        if (lane < 36) {
            float4 o = *reinterpret_cast<const float4*>(&sOut[lane * 4]);
            *reinterpret_cast<float4*>(out + (size_t)bc * 144 + lane * 4) = o;
        }
    }
}

extern "C" void kernel_launch(void* const* d_in, const int* in_sizes, int n_in,
                              void* d_out, int out_size, void* d_ws, size_t ws_size,
                              hipStream_t stream) {
    const float* vec = (const float*)d_in[0];  // (4096,3) f32
    const float* img = (const float*)d_in[1];  // (4096,2,128,128) f32
    float* out = (float*)d_out;                // (4096,2,12,12) f32
    (void)in_sizes; (void)n_in; (void)out_size; (void)d_ws; (void)ws_size;

    glimpse_kernel<<<8192, 256, 0, stream>>>(vec, img, out);
}